// Round 9
// baseline (273.969 us; speedup 1.0000x reference)
//
#include <hip/hip_runtime.h>

// Segment-sum over sorted ray indices + gather-back, no atomics.
//   d_in[0]: sample_values f32 [n_samples * D]
//   d_in[1]: ray_indices  i32 [n_samples] (sorted, non-decreasing)
//   d_in[2]: n_rays (device scalar, unused -- derived from sizes)
//   d_out  : [n_rays*D] per-ray sums, then [n_samples*D] per-sample gathered sums
//
// Kernel A (bounds): boundary threads write seg_start/seg_end AND fill empty
//   rays with start==end (zero-length) -> no memset pass, no -1 sentinels.
// Kernel B (raysum): one wave per 8 rays. Bounds for all 8 rays loaded with
//   one coalesced pair of loads (amortizes the ~1200-cyc dependent prologue
//   that limited the previous version to 2.4 TB/s). Stream is float4:
//   2 lanes per sample, 1 KB per load instruction. Per ray: reduce via 5-step
//   shfl_xor, plain store of the per-ray sum, nontemporal broadcast stores of
//   the per-sample copies (write-only stream, keep it out of L2).

#define DCH 8
#define RPW 8  // rays per wave

typedef float f32x4 __attribute__((ext_vector_type(4)));

__global__ void __launch_bounds__(256) bounds_kernel(
    const int* __restrict__ rays,
    int* __restrict__ seg_start,
    int* __restrict__ seg_end,
    int n_samples, int n_rays) {
  long i = (long)blockIdx.x * blockDim.x + threadIdx.x;
  if (i >= n_samples) return;
  int r = rays[i];
  if (i == 0) {
    seg_start[r] = 0;
    for (int g = 0; g < r; ++g) { seg_start[g] = 0; seg_end[g] = 0; }
  } else {
    int rp = rays[i - 1];
    if (rp != r) {
      seg_end[rp] = (int)i;
      seg_start[r] = (int)i;
      for (int g = rp + 1; g < r; ++g) { seg_start[g] = (int)i; seg_end[g] = (int)i; }
    }
  }
  if (i == n_samples - 1) {
    seg_end[r] = n_samples;
    for (int g = r + 1; g < n_rays; ++g) { seg_start[g] = n_samples; seg_end[g] = n_samples; }
  }
}

__global__ void __launch_bounds__(256) raysum_kernel(
    const f32x4* __restrict__ vals4,
    const int* __restrict__ seg_start,
    const int* __restrict__ seg_end,
    f32x4* __restrict__ out_ray4,
    f32x4* __restrict__ out_sample4,
    int n_rays) {
  const int wave = blockIdx.x * (blockDim.x >> 6) + (threadIdx.x >> 6);
  const int base = wave * RPW;
  if (base >= n_rays) return;
  const int lane = threadIdx.x & 63;
  const int sl = lane >> 1;  // sample slot within window [0,32)
  const int h = lane & 1;    // float4 half of the 32B sample

  // Coalesced bounds prefetch for this wave's 8 rays (one 32B segment each).
  const int ridx = base + (lane & (RPW - 1));
  int rs = 0, re = 0;
  if (ridx < n_rays) {
    rs = seg_start[ridx];
    re = seg_end[ridx];
  }

#pragma unroll 1
  for (int r = 0; r < RPW; ++r) {
    if (base + r >= n_rays) break;
    const int s0 = __shfl(rs, r, 64);
    const int s1 = __shfl(re, r, 64);

    f32x4 acc = {0.f, 0.f, 0.f, 0.f};
    for (int j = s0 + sl; j < s1; j += 32) {
      f32x4 v = vals4[(long)j * 2 + h];
      acc += v;
    }

    // Reduce across the 32 sample slots (lane bits 1..5); each lane ends with
    // the full ray sum for its float4 half.
#pragma unroll
    for (int off = 2; off <= 32; off <<= 1) {
      acc.x += __shfl_xor(acc.x, off, 64);
      acc.y += __shfl_xor(acc.y, off, 64);
      acc.z += __shfl_xor(acc.z, off, 64);
      acc.w += __shfl_xor(acc.w, off, 64);
    }

    // Per-ray sum: lanes 0 (h=0) and 1 (h=1) hold the two halves.
    if (lane < 2) {
      out_ray4[(long)(base + r) * 2 + lane] = acc;
    }

    // Broadcast the ray sum back over this ray's samples. Nontemporal: this
    // 130 MB stream is write-only, keep it from evicting vals from L2/L3.
    for (int j = s0 + sl; j < s1; j += 32) {
      __builtin_nontemporal_store(acc, &out_sample4[(long)j * 2 + h]);
    }
  }
}

extern "C" void kernel_launch(void* const* d_in, const int* in_sizes, int n_in,
                              void* d_out, int out_size, void* d_ws, size_t ws_size,
                              hipStream_t stream) {
  const float* vals = (const float*)d_in[0];
  const int* rays   = (const int*)d_in[1];

  const int n_samples = in_sizes[1];
  const int d         = in_sizes[0] / n_samples;   // = 8
  const int n_rays    = out_size / d - n_samples;  // = 65536

  float* out_ray    = (float*)d_out;
  float* out_sample = out_ray + (size_t)n_rays * d;

  int* seg_start = (int*)d_ws;
  int* seg_end   = seg_start + n_rays;

  bounds_kernel<<<(int)(((long)n_samples + 255) / 256), 256, 0, stream>>>(
      rays, seg_start, seg_end, n_samples, n_rays);

  // One wave per 8 rays: 8192 waves, 4 waves per 256-thread block.
  const int nwaves = (n_rays + RPW - 1) / RPW;
  const int nblocks = (nwaves + 3) / 4;
  raysum_kernel<<<nblocks, 256, 0, stream>>>(
      reinterpret_cast<const f32x4*>(vals), seg_start, seg_end,
      reinterpret_cast<f32x4*>(out_ray),
      reinterpret_cast<f32x4*>(out_sample), n_rays);
}